// Round 15
// baseline (46327.625 us; speedup 1.0000x reference)
//
#include <hip/hip_runtime.h>
#include <hip/hip_bf16.h>

// LSTM: V=50000, E=512, H=512, S=16384, batch=1.
// Phase 1: gx[t][unit][gate] = emb[x[t]].W_ih + (b_ih+b_hh), bf16.
// Phase 2: 128 wgs. Participants = wg%8==0 (16 ranks; under round-robin
//          dispatch all on XCD 0). 4-round budgeted handshake with the real
//          sc0 primitives picks FAST (same-XCD L2 sc0 exchange) vs SLOW
//          (R14 agent path). Burners on wg%8!=0 && wg<64 keep clocks awake.
//          h exchange: 4B words (tag16|bf16), LDS stage -> ONE 128B line/wg.
// Phase 3: head MLP on rank 0.

#define S_LEN 16384
#define NWG   16
#define NLAUNCH 128
#define NTHR  512

typedef unsigned long long u64;
typedef float float4v __attribute__((ext_vector_type(4)));

static __device__ __forceinline__ float bf2f(unsigned int u16) {
  union { unsigned int i; float f; } v; v.i = u16 << 16; return v.f;
}
static __device__ __forceinline__ unsigned short f2bf(float f) {
  union { float f; unsigned int i; } v; v.f = f;
  unsigned int r = v.i + 0x7fffu + ((v.i >> 16) & 1u);
  return (unsigned short)(r >> 16);
}
static __device__ __forceinline__ float fsig(float x) { return 1.f / (1.f + __expf(-x)); }
static __device__ __forceinline__ float ftanh(float x) { return 2.f / (1.f + __expf(-2.f * x)) - 1.f; }

// LDS hbuf: h[k] at k + (k>>4)  (stride-17 rows: conflict-free)
static __device__ __forceinline__ int haddr(int k) { return k + (k >> 4); }

// ---- sc0 primitives (bypass L1; same-XCD L2 visibility) ----
static __device__ __forceinline__ u64 ld_sc0(const u64* p) {
  u64 v;
  asm volatile("global_load_dwordx2 %0, %1, off sc0\n\ts_waitcnt vmcnt(0)"
               : "=v"(v) : "v"((u64)p) : "memory");
  return v;
}
static __device__ __forceinline__ void st_sc0(u64* p, u64 w) {
  asm volatile("global_store_dwordx2 %0, %1, off sc0"
               :: "v"((u64)p), "v"(w) : "memory");
}
static __device__ __forceinline__ void poll4_sc0(const u64* base, int lane, u64 v[4]) {
  u64 a = (u64)base + (u64)lane * 8ull;
  asm volatile(
      "global_load_dwordx2 %[v0], %[ad], off sc0\n\t"
      "global_load_dwordx2 %[v1], %[ad], off offset:512 sc0\n\t"
      "global_load_dwordx2 %[v2], %[ad], off offset:1024 sc0\n\t"
      "global_load_dwordx2 %[v3], %[ad], off offset:1536 sc0\n\t"
      "s_waitcnt vmcnt(0)"
      : [v0] "=&v"(v[0]), [v1] "=&v"(v[1]), [v2] "=&v"(v[2]), [v3] "=&v"(v[3])
      : [ad] "v"(a)
      : "memory");
}

// ---------------- Phase 1: gx GEMM ----------------
__global__ __launch_bounds__(256, 2) void gx_gemm(
    const int* __restrict__ x, const float* __restrict__ emb,
    const float* __restrict__ W_ih, const float* __restrict__ b_ih,
    const float* __restrict__ b_hh, unsigned short* __restrict__ gx)
{
  __shared__ float As[64][40];
  __shared__ float Bs[64][40];
  __shared__ int   xs[64];

  const int tid = threadIdx.x;
  const int bm = blockIdx.x;
  const int bn = blockIdx.y;

  if (tid < 64) xs[tid] = x[bm * 64 + tid];
  __syncthreads();

  float acc[4][4] = {};
  const int r0 = (tid >> 4) * 4;
  const int c0 = tid & 15;

  for (int kc = 0; kc < 512; kc += 32) {
#pragma unroll
    for (int h = 0; h < 2; ++h) {
      const int v = tid + h * 256;
      const int row = v >> 3, k4 = v & 7;
      const float4 av = *(const float4*)(emb + (size_t)xs[row] * 512 + kc + k4 * 4);
      As[row][k4 * 4 + 0] = av.x; As[row][k4 * 4 + 1] = av.y;
      As[row][k4 * 4 + 2] = av.z; As[row][k4 * 4 + 3] = av.w;
      const float4 bv = *(const float4*)(W_ih + (size_t)(bn * 64 + row) * 512 + kc + k4 * 4);
      Bs[row][k4 * 4 + 0] = bv.x; Bs[row][k4 * 4 + 1] = bv.y;
      Bs[row][k4 * 4 + 2] = bv.z; Bs[row][k4 * 4 + 3] = bv.w;
    }
    __syncthreads();
#pragma unroll
    for (int k4 = 0; k4 < 8; ++k4) {
      float4 a[4], b[4];
#pragma unroll
      for (int i = 0; i < 4; ++i) a[i] = *(const float4*)&As[r0 + i][k4 * 4];
#pragma unroll
      for (int j = 0; j < 4; ++j) b[j] = *(const float4*)&Bs[c0 + j * 16][k4 * 4];
#pragma unroll
      for (int i = 0; i < 4; ++i)
#pragma unroll
        for (int j = 0; j < 4; ++j) {
          acc[i][j] = __builtin_fmaf(a[i].x, b[j].x, acc[i][j]);
          acc[i][j] = __builtin_fmaf(a[i].y, b[j].y, acc[i][j]);
          acc[i][j] = __builtin_fmaf(a[i].z, b[j].z, acc[i][j]);
          acc[i][j] = __builtin_fmaf(a[i].w, b[j].w, acc[i][j]);
        }
    }
    __syncthreads();
  }

  // layout [t][unit][gate]: dst = t*2048 + (c&511)*4 + (c>>9)
#pragma unroll
  for (int j = 0; j < 4; ++j) {
    const int c = bn * 64 + c0 + j * 16;
    const float bias = b_ih[c] + b_hh[c];
    const size_t dstc = (size_t)(c & 511) * 4 + (size_t)(c >> 9);
#pragma unroll
    for (int i = 0; i < 4; ++i) {
      const size_t t = (size_t)bm * 64 + r0 + i;
      gx[t * 2048 + dstc] = f2bf(acc[i][j] + bias);
    }
  }
}

// ---------------- Phase 2: recurrence (fast sc0 / slow agent) ----------------
// h32: [2 buf][512] u32 = (tag16<<16) | bf16(h).  One 128B line per rank.
__global__ __launch_bounds__(NTHR, 1) void lstm_rec(
    const float* __restrict__ W_hh, const unsigned short* __restrict__ gx,
    const float* __restrict__ W1, const float* __restrict__ b1,
    const float* __restrict__ W2, const float* __restrict__ b2,
    float* __restrict__ out,
    unsigned int* __restrict__ h32,
    u64* __restrict__ hs,              // [16] handshake tags
    unsigned int* __restrict__ ver,    // [0]=nfail [1]=ndone [2]=modeword
    unsigned int* __restrict__ done)   // burner flags, 32B apart
{
  const int tid = threadIdx.x;
  const int wg  = blockIdx.x;

  if (wg & 7) {
    // ---- burners (wg<64) keep clocks awake; others exit ----
    if (wg >= 64) return;
    unsigned int* myflag = done + wg * 8;
    float a0 = (float)tid, a1 = a0 + 1.f, a2 = a0 + 2.f, a3 = a0 + 3.f;
    for (;;) {
      if (__hip_atomic_load(myflag, __ATOMIC_RELAXED, __HIP_MEMORY_SCOPE_AGENT))
        break;
#pragma unroll 32
      for (int i = 0; i < 2048; ++i) {
        a0 = __builtin_fmaf(a0, 1.0000001f, 1e-9f);
        a1 = __builtin_fmaf(a1, 0.9999999f, 1e-9f);
        a2 = __builtin_fmaf(a2, 1.0000002f, 1e-9f);
        a3 = __builtin_fmaf(a3, 0.9999998f, 1e-9f);
      }
    }
    asm volatile("" :: "v"(a0), "v"(a1), "v"(a2), "v"(a3));
    return;
  }

  const int w = wg >> 3;               // rank 0..15 (all on one XCD if RR)
  const int s    = tid & 31;
  const int half = (tid >> 5) & 1;
  const int wvi  = tid >> 6;
  const int ubase  = w * 32 + wvi * 4 + half * 2;
  const int ulocal = wvi * 4 + half * 2;

  // ---- weights pinned in regs via asm loads ----
  float4v wvv[32];
#pragma unroll
  for (int q = 0; q < 8; ++q) {
    const int row = (q & 3) * 512 + ubase + (q >> 2);
    const float* src = W_hh + (size_t)row * 512 + s * 16;
#pragma unroll
    for (int i4 = 0; i4 < 4; ++i4) {
      asm volatile("global_load_dwordx4 %0, %1, off\n\ts_waitcnt vmcnt(0)"
                   : "=v"(wvv[q * 4 + i4]) : "v"((u64)(src + i4 * 4)) : "memory");
    }
  }

  // ---- handshake: validate sc0 exchange with steady-state primitives ----
  __shared__ int mode_sh;
  if (tid < 64) {
    bool fastok = true;
    int budget = 8000;
    for (int round = 1; round <= 4; ++round) {
      if (tid == 0)
        st_sc0(&hs[w], ((u64)(unsigned)round << 32) | (unsigned)w);
      if (!fastok) continue;   // keep storing so others can finish their rounds
      bool ok = false;
      while (budget > 0) {
        --budget;
        u64 v = 0;
        if (tid < 16) v = ld_sc0(&hs[tid]);
        const bool lok = (tid < 16) ? ((unsigned)(v >> 32) >= (unsigned)round) : true;
        if (__all(lok)) { ok = true; break; }
      }
      if (!ok) fastok = false;
    }
    if (tid == 0) mode_sh = fastok ? 1 : 0;
  }
  __syncthreads();
  if (tid == 0) {
    const unsigned myfail = mode_sh ? 0u : 1u;
    __hip_atomic_fetch_add(&ver[0], myfail, __ATOMIC_RELAXED, __HIP_MEMORY_SCOPE_AGENT);
    __hip_atomic_fetch_add(&ver[1], 1u, __ATOMIC_RELEASE, __HIP_MEMORY_SCOPE_AGENT);
    if (w == 0) {
      while (__hip_atomic_load(&ver[1], __ATOMIC_ACQUIRE, __HIP_MEMORY_SCOPE_AGENT) < NWG) {}
      const unsigned nf = __hip_atomic_load(&ver[0], __ATOMIC_RELAXED, __HIP_MEMORY_SCOPE_AGENT);
      __hip_atomic_store(&ver[2], 0x100u | (nf == 0u ? 1u : 0u),
                         __ATOMIC_RELAXED, __HIP_MEMORY_SCOPE_AGENT);
    }
    unsigned mw;
    do {
      mw = __hip_atomic_load(&ver[2], __ATOMIC_RELAXED, __HIP_MEMORY_SCOPE_AGENT);
    } while (!(mw & 0x100u));
    mode_sh = (int)(mw & 1u);
  }
  __syncthreads();
  const int mode = mode_sh;            // launch-uniform

  __shared__ float hbuf[2][544];
  __shared__ unsigned int stage[32];

  float c0 = 0.f, c1 = 0.f;
  float h_reg[16];
#pragma unroll
  for (int i = 0; i < 16; ++i) h_reg[i] = 0.f;

  uint4 g_cur = {0,0,0,0}, g_nxt = {0,0,0,0};
  if (s == 0) {
    g_cur = *(const uint4*)(gx + (size_t)0 * 2048 + ubase * 4);
    g_nxt = *(const uint4*)(gx + (size_t)1 * 2048 + ubase * 4);
  }

  for (int t = 0; t < S_LEN; ++t) {
    uint4 g_new = {0,0,0,0};
    if (s == 0 && t + 2 < S_LEN)
      g_new = *(const uint4*)(gx + (size_t)(t + 2) * 2048 + ubase * 4);

    float acc[8];
#pragma unroll
    for (int q = 0; q < 8; ++q) {
      float a = 0.f;
#pragma unroll
      for (int i4 = 0; i4 < 4; ++i4) {
        const float4v vv = wvv[q * 4 + i4];
        a = __builtin_fmaf(vv.x, h_reg[i4 * 4 + 0], a);
        a = __builtin_fmaf(vv.y, h_reg[i4 * 4 + 1], a);
        a = __builtin_fmaf(vv.z, h_reg[i4 * 4 + 2], a);
        a = __builtin_fmaf(vv.w, h_reg[i4 * 4 + 3], a);
      }
      acc[q] = a;
    }
#pragma unroll
    for (int q = 0; q < 8; ++q) {
      float a = acc[q];
      a += __shfl_xor(a, 1);
      a += __shfl_xor(a, 2);
      a += __shfl_xor(a, 4);
      a += __shfl_xor(a, 8);
      a += __shfl_xor(a, 16);
      acc[q] = a;
    }

    const int buf = (t + 1) & 1;
    if (s == 0) {
      const float pi0 = acc[0] + bf2f(g_cur.x & 0xffffu);
      const float pf0 = acc[1] + bf2f(g_cur.x >> 16);
      const float pg0 = acc[2] + bf2f(g_cur.y & 0xffffu);
      const float po0 = acc[3] + bf2f(g_cur.y >> 16);
      const float pi1 = acc[4] + bf2f(g_cur.z & 0xffffu);
      const float pf1 = acc[5] + bf2f(g_cur.z >> 16);
      const float pg1 = acc[6] + bf2f(g_cur.w & 0xffffu);
      const float po1 = acc[7] + bf2f(g_cur.w >> 16);
      c0 = fsig(pf0) * c0 + fsig(pi0) * ftanh(pg0);
      c1 = fsig(pf1) * c1 + fsig(pi1) * ftanh(pg1);
      const float h0 = fsig(po0) * ftanh(c0);
      const float h1 = fsig(po1) * ftanh(c1);
      const unsigned tg16 = (unsigned)(t + 1) << 16;
      const u64 pk = ((u64)(tg16 | (unsigned)f2bf(h1)) << 32)
                   |  (u64)(tg16 | (unsigned)f2bf(h0));
      *(u64*)&stage[ulocal] = pk;
    }
    __syncthreads();  // S1 — stage complete

    if (tid < 64) {
      // condensed publish: ONE instruction, 16 lanes x 8B = the rank's 128B line
      if (tid < 16) {
        const u64 sv = *(const u64*)&stage[tid * 2];
        u64* dst = (u64*)&h32[buf * 512 + w * 32] + tid;
        if (mode) st_sc0(dst, sv);
        else __hip_atomic_store(dst, sv, __ATOMIC_RELAXED, __HIP_MEMORY_SCOPE_AGENT);
      }
      if (t + 1 < S_LEN) {
        const u64* hb = (const u64*)(h32 + buf * 512);
        const unsigned want = (unsigned)(t + 1) & 0xffffu;
        u64 v[4];
        if (mode) {
          for (;;) {
            poll4_sc0(hb, tid, v);
            bool ok = true;
#pragma unroll
            for (int j = 0; j < 4; ++j) {
              ok &= (((unsigned)(v[j] >> 16) & 0xffffu) == want);
              ok &= ((unsigned)(v[j] >> 48) == want);
            }
            if (__all(ok)) break;
          }
        } else {
          for (;;) {
#pragma unroll
            for (int j = 0; j < 4; ++j)
              v[j] = __hip_atomic_load(&hb[j * 64 + tid],
                                       __ATOMIC_RELAXED, __HIP_MEMORY_SCOPE_AGENT);
            bool ok = true;
#pragma unroll
            for (int j = 0; j < 4; ++j) {
              ok &= (((unsigned)(v[j] >> 16) & 0xffffu) == want);
              ok &= ((unsigned)(v[j] >> 48) == want);
            }
            if (__all(ok)) break;
          }
        }
#pragma unroll
        for (int j = 0; j < 4; ++j) {
          const int k = (j * 64 + tid) * 2;
          union { unsigned u; float f; } f0, f1;
          f0.u = ((unsigned)v[j]) << 16;
          f1.u = ((unsigned)(v[j] >> 32)) << 16;
          hbuf[buf][haddr(k)]     = f0.f;
          hbuf[buf][haddr(k + 1)] = f1.f;
        }
      }
    }
    __syncthreads();  // S2 — h_{t+1} staged in LDS

    if (t + 1 < S_LEN) {
      const int base = s * 17;
#pragma unroll
      for (int i = 0; i < 16; ++i)
        h_reg[i] = hbuf[buf][base + i];
    }

    g_cur = g_nxt; g_nxt = g_new;
  }

  // stop burners: rank0 fans out private flags (covers wg<64)
  if (w == 0 && tid < 64)
    __hip_atomic_store(done + tid * 8, 1u,
                       __ATOMIC_RELAXED, __HIP_MEMORY_SCOPE_AGENT);

  // ---------------- Phase 3: head (rank 0) ----------------
  if (w == 0) {
    __shared__ float hl[512];
    __shared__ float zl[128];
    {
      unsigned v;
      if (mode) {
        // fast: words written sc0; read pairwise via sc0
        const u64* hb = (const u64*)h32;
        u64 pv;
        do { pv = ld_sc0(&hb[tid >> 1]); }
        while (((unsigned)(pv >> 16) & 0xffffu) != (unsigned)S_LEN ||
               ((unsigned)(pv >> 48)) != (unsigned)S_LEN);
        v = (tid & 1) ? (unsigned)(pv >> 32) : (unsigned)pv;
      } else {
        do {
          v = __hip_atomic_load(&h32[tid], __ATOMIC_RELAXED, __HIP_MEMORY_SCOPE_AGENT);
        } while ((v >> 16) != (unsigned)S_LEN);
      }
      union { unsigned u; float f; } hu; hu.u = v << 16;
      hl[tid] = hu.f;
    }
    __syncthreads();
    const int j = tid >> 2, q = tid & 3;
    float sum = 0.f;
    const float4* w1v = (const float4*)(W1 + (size_t)j * 512 + q * 128);
#pragma unroll 8
    for (int k4 = 0; k4 < 32; ++k4) {
      const float4 v = w1v[k4];
      const int kb = q * 128 + k4 * 4;
      sum = __builtin_fmaf(v.x, hl[kb + 0], sum);
      sum = __builtin_fmaf(v.y, hl[kb + 1], sum);
      sum = __builtin_fmaf(v.z, hl[kb + 2], sum);
      sum = __builtin_fmaf(v.w, hl[kb + 3], sum);
    }
    sum += __shfl_xor(sum, 1);
    sum += __shfl_xor(sum, 2);
    if (q == 0) zl[j] = fsig(sum + b1[j]);
    __syncthreads();
    if (tid < 9) {
      float o = b2[tid];
      const float* w2r = W2 + tid * 128;
#pragma unroll 16
      for (int k = 0; k < 128; ++k) o = __builtin_fmaf(w2r[k], zl[k], o);
      out[tid] = fsig(o);
    }
  }
}

extern "C" void kernel_launch(void* const* d_in, const int* in_sizes, int n_in,
                              void* d_out, int out_size, void* d_ws, size_t ws_size,
                              hipStream_t stream) {
  const int*   x     = (const int*)d_in[0];
  const float* emb   = (const float*)d_in[1];
  const float* W_ih  = (const float*)d_in[2];
  const float* W_hh  = (const float*)d_in[3];
  const float* b_ih  = (const float*)d_in[4];
  const float* b_hh  = (const float*)d_in[5];
  const float* W1    = (const float*)d_in[6];
  const float* b1    = (const float*)d_in[7];
  const float* W2    = (const float*)d_in[8];
  const float* b2    = (const float*)d_in[9];
  float* out = (float*)d_out;

  const size_t gx_bytes = (size_t)S_LEN * 2048 * sizeof(unsigned short); // 64 MB
  const size_t h_off  = gx_bytes;          // h32: 4 KB
  const size_t hs_off = h_off + 4096;      // hs: 128 B
  const size_t vr_off = h_off + 4352;      // ver: 64 B
  const size_t dn_off = h_off + 4608;      // done: 64*32 B
  if (ws_size < h_off + 16384) return;  // fail visibly

  unsigned short* gxp  = (unsigned short*)d_ws;
  unsigned int*   h32  = (unsigned int*)((char*)d_ws + h_off);
  u64*            hsp  = (u64*)((char*)d_ws + hs_off);
  unsigned int*   verp = (unsigned int*)((char*)d_ws + vr_off);
  unsigned int*   done = (unsigned int*)((char*)d_ws + dn_off);

  // reset all sync state every launch (graph replays don't re-poison ws)
  (void)hipMemsetAsync((char*)d_ws + h_off, 0, 16384, stream);

  dim3 g1(S_LEN / 64, 2048 / 64);
  gx_gemm<<<g1, 256, 0, stream>>>(x, emb, W_ih, b_ih, b_hh, gxp);
  lstm_rec<<<NLAUNCH, NTHR, 0, stream>>>(W_hh, gxp, W1, b1, W2, b2, out,
                                         h32, hsp, verp, done);
}

// Round 16
// 44473.795 us; speedup vs baseline: 1.0417x; 1.0417x over previous
//
#include <hip/hip_runtime.h>
#include <hip/hip_bf16.h>

// LSTM: V=50000, E=512, H=512, S=16384, batch=1.
// Phase 1: gx[t][unit][gate] = emb[x[t]].W_ih + (b_ih+b_hh), bf16.
// Phase 2: 64 wgs: wg 0..15 = persistent recurrence; wg 16..63 = burners.
//          h exchange: 4B words (tag16<<16 | bf16 h); LDS stage -> ONE 128B-line
//          store per wg; poller wave uses 2-deep PIPELINED polling (vmcnt(4))
//          to cut detect latency below one IC round-trip; LDS bcast.
// Phase 3: head MLP on wg 0.

#define S_LEN 16384
#define NWG   16
#define NLAUNCH 64
#define NTHR  512

typedef unsigned long long u64;
typedef float float4v __attribute__((ext_vector_type(4)));

static __device__ __forceinline__ float bf2f(unsigned int u16) {
  union { unsigned int i; float f; } v; v.i = u16 << 16; return v.f;
}
static __device__ __forceinline__ unsigned short f2bf(float f) {
  union { float f; unsigned int i; } v; v.f = f;
  unsigned int r = v.i + 0x7fffu + ((v.i >> 16) & 1u);
  return (unsigned short)(r >> 16);
}
static __device__ __forceinline__ float fsig(float x) { return 1.f / (1.f + __expf(-x)); }
static __device__ __forceinline__ float ftanh(float x) { return 2.f / (1.f + __expf(-2.f * x)) - 1.f; }

// LDS hbuf: h[k] at k + (k>>4)  (stride-17 rows: conflict-free)
static __device__ __forceinline__ int haddr(int k) { return k + (k >> 4); }

// issue 4 agent-scope loads (L1+L2 bypass), NO wait — caller manages vmcnt
#define ISSUE4(dst, ad)                                                     \
  asm volatile(                                                             \
      "global_load_dwordx2 %[v0], %[a], off sc0 sc1\n\t"                    \
      "global_load_dwordx2 %[v1], %[a], off offset:512 sc0 sc1\n\t"         \
      "global_load_dwordx2 %[v2], %[a], off offset:1024 sc0 sc1\n\t"        \
      "global_load_dwordx2 %[v3], %[a], off offset:1536 sc0 sc1"            \
      : [v0] "=&v"(dst[0]), [v1] "=&v"(dst[1]),                             \
        [v2] "=&v"(dst[2]), [v3] "=&v"(dst[3])                              \
      : [a] "v"(ad) : "memory")

// ---------------- Phase 1: gx GEMM ----------------
__global__ __launch_bounds__(256, 2) void gx_gemm(
    const int* __restrict__ x, const float* __restrict__ emb,
    const float* __restrict__ W_ih, const float* __restrict__ b_ih,
    const float* __restrict__ b_hh, unsigned short* __restrict__ gx)
{
  __shared__ float As[64][40];
  __shared__ float Bs[64][40];
  __shared__ int   xs[64];

  const int tid = threadIdx.x;
  const int bm = blockIdx.x;
  const int bn = blockIdx.y;

  if (tid < 64) xs[tid] = x[bm * 64 + tid];
  __syncthreads();

  float acc[4][4] = {};
  const int r0 = (tid >> 4) * 4;
  const int c0 = tid & 15;

  for (int kc = 0; kc < 512; kc += 32) {
#pragma unroll
    for (int h = 0; h < 2; ++h) {
      const int v = tid + h * 256;
      const int row = v >> 3, k4 = v & 7;
      const float4 av = *(const float4*)(emb + (size_t)xs[row] * 512 + kc + k4 * 4);
      As[row][k4 * 4 + 0] = av.x; As[row][k4 * 4 + 1] = av.y;
      As[row][k4 * 4 + 2] = av.z; As[row][k4 * 4 + 3] = av.w;
      const float4 bv = *(const float4*)(W_ih + (size_t)(bn * 64 + row) * 512 + kc + k4 * 4);
      Bs[row][k4 * 4 + 0] = bv.x; Bs[row][k4 * 4 + 1] = bv.y;
      Bs[row][k4 * 4 + 2] = bv.z; Bs[row][k4 * 4 + 3] = bv.w;
    }
    __syncthreads();
#pragma unroll
    for (int k4 = 0; k4 < 8; ++k4) {
      float4 a[4], b[4];
#pragma unroll
      for (int i = 0; i < 4; ++i) a[i] = *(const float4*)&As[r0 + i][k4 * 4];
#pragma unroll
      for (int j = 0; j < 4; ++j) b[j] = *(const float4*)&Bs[c0 + j * 16][k4 * 4];
#pragma unroll
      for (int i = 0; i < 4; ++i)
#pragma unroll
        for (int j = 0; j < 4; ++j) {
          acc[i][j] = __builtin_fmaf(a[i].x, b[j].x, acc[i][j]);
          acc[i][j] = __builtin_fmaf(a[i].y, b[j].y, acc[i][j]);
          acc[i][j] = __builtin_fmaf(a[i].z, b[j].z, acc[i][j]);
          acc[i][j] = __builtin_fmaf(a[i].w, b[j].w, acc[i][j]);
        }
    }
    __syncthreads();
  }

  // layout [t][unit][gate]: dst = t*2048 + (c&511)*4 + (c>>9)
#pragma unroll
  for (int j = 0; j < 4; ++j) {
    const int c = bn * 64 + c0 + j * 16;
    const float bias = b_ih[c] + b_hh[c];
    const size_t dstc = (size_t)(c & 511) * 4 + (size_t)(c >> 9);
#pragma unroll
    for (int i = 0; i < 4; ++i) {
      const size_t t = (size_t)bm * 64 + r0 + i;
      gx[t * 2048 + dstc] = f2bf(acc[i][j] + bias);
    }
  }
}

// ---------------- Phase 2: recurrence + light burners ----------------
// h32: [2 buf][512] u32 = (tag16<<16) | bf16(h).  One 128B line per wg.
__global__ __launch_bounds__(NTHR, 1) void lstm_rec(
    const float* __restrict__ W_hh, const unsigned short* __restrict__ gx,
    const float* __restrict__ W1, const float* __restrict__ b1,
    const float* __restrict__ W2, const float* __restrict__ b2,
    float* __restrict__ out,
    unsigned int* __restrict__ h32,
    unsigned int* __restrict__ done)
{
  const int tid = threadIdx.x;
  const int w   = blockIdx.x;

  // ---- burners: keep clocks awake; private flag, long burn interval ----
  if (w >= NWG) {
    unsigned int* myflag = done + (w - NWG) * 8;
    float a0 = (float)tid, a1 = a0 + 1.f, a2 = a0 + 2.f, a3 = a0 + 3.f;
    for (;;) {
      if (__hip_atomic_load(myflag, __ATOMIC_RELAXED, __HIP_MEMORY_SCOPE_AGENT))
        break;
#pragma unroll 32
      for (int i = 0; i < 2048; ++i) {
        a0 = __builtin_fmaf(a0, 1.0000001f, 1e-9f);
        a1 = __builtin_fmaf(a1, 0.9999999f, 1e-9f);
        a2 = __builtin_fmaf(a2, 1.0000002f, 1e-9f);
        a3 = __builtin_fmaf(a3, 0.9999998f, 1e-9f);
      }
    }
    asm volatile("" :: "v"(a0), "v"(a1), "v"(a2), "v"(a3));  // keep live
    return;
  }

  const int s    = tid & 31;          // K-slice: k in [s*16, s*16+16)
  const int half = (tid >> 5) & 1;
  const int wvi  = tid >> 6;          // wave 0..7
  const int ubase  = w * 32 + wvi * 4 + half * 2;
  const int ulocal = wvi * 4 + half * 2;

  // ---- weights pinned in regs via asm loads (non-rematerializable) ----
  float4v wvv[32];
#pragma unroll
  for (int q = 0; q < 8; ++q) {
    const int row = (q & 3) * 512 + ubase + (q >> 2);
    const float* src = W_hh + (size_t)row * 512 + s * 16;
#pragma unroll
    for (int i4 = 0; i4 < 4; ++i4) {
      asm volatile("global_load_dwordx4 %0, %1, off\n\ts_waitcnt vmcnt(0)"
                   : "=v"(wvv[q * 4 + i4]) : "v"((u64)(src + i4 * 4)) : "memory");
    }
  }

  __shared__ float hbuf[2][544];
  __shared__ unsigned int stage[32];

  float c0 = 0.f, c1 = 0.f;
  float h_reg[16];
#pragma unroll
  for (int i = 0; i < 16; ++i) h_reg[i] = 0.f;

  uint4 g_cur = {0,0,0,0}, g_nxt = {0,0,0,0};
  if (s == 0) {
    g_cur = *(const uint4*)(gx + (size_t)0 * 2048 + ubase * 4);
    g_nxt = *(const uint4*)(gx + (size_t)1 * 2048 + ubase * 4);
  }

  for (int t = 0; t < S_LEN; ++t) {
    uint4 g_new = {0,0,0,0};
    if (s == 0 && t + 2 < S_LEN)
      g_new = *(const uint4*)(gx + (size_t)(t + 2) * 2048 + ubase * 4);

    float acc[8];
#pragma unroll
    for (int q = 0; q < 8; ++q) {
      float a = 0.f;
#pragma unroll
      for (int i4 = 0; i4 < 4; ++i4) {
        const float4v vv = wvv[q * 4 + i4];
        a = __builtin_fmaf(vv.x, h_reg[i4 * 4 + 0], a);
        a = __builtin_fmaf(vv.y, h_reg[i4 * 4 + 1], a);
        a = __builtin_fmaf(vv.z, h_reg[i4 * 4 + 2], a);
        a = __builtin_fmaf(vv.w, h_reg[i4 * 4 + 3], a);
      }
      acc[q] = a;
    }
#pragma unroll
    for (int q = 0; q < 8; ++q) {
      float a = acc[q];
      a += __shfl_xor(a, 1);
      a += __shfl_xor(a, 2);
      a += __shfl_xor(a, 4);
      a += __shfl_xor(a, 8);
      a += __shfl_xor(a, 16);
      acc[q] = a;
    }

    const int buf = (t + 1) & 1;
    if (s == 0) {
      const float pi0 = acc[0] + bf2f(g_cur.x & 0xffffu);
      const float pf0 = acc[1] + bf2f(g_cur.x >> 16);
      const float pg0 = acc[2] + bf2f(g_cur.y & 0xffffu);
      const float po0 = acc[3] + bf2f(g_cur.y >> 16);
      const float pi1 = acc[4] + bf2f(g_cur.z & 0xffffu);
      const float pf1 = acc[5] + bf2f(g_cur.z >> 16);
      const float pg1 = acc[6] + bf2f(g_cur.w & 0xffffu);
      const float po1 = acc[7] + bf2f(g_cur.w >> 16);
      c0 = fsig(pf0) * c0 + fsig(pi0) * ftanh(pg0);
      c1 = fsig(pf1) * c1 + fsig(pi1) * ftanh(pg1);
      const float h0 = fsig(po0) * ftanh(c0);
      const float h1 = fsig(po1) * ftanh(c1);
      const unsigned tg16 = (unsigned)(t + 1) << 16;
      const u64 pk = ((u64)(tg16 | (unsigned)f2bf(h1)) << 32)
                   |  (u64)(tg16 | (unsigned)f2bf(h0));
      *(u64*)&stage[ulocal] = pk;     // 8B aligned (ulocal even)
    }
    __syncthreads();  // S1 — stage complete

    if (tid < 64) {
      // condensed publish: ONE instruction, 16 lanes x 8B = the wg's 128B line
      if (tid < 16) {
        const u64 sv = *(const u64*)&stage[tid * 2];
        __hip_atomic_store((u64*)&h32[buf * 512 + w * 32] + tid, sv,
                           __ATOMIC_RELAXED, __HIP_MEMORY_SCOPE_AGENT);
      }
      if (t + 1 < S_LEN) {
        // -------- 2-deep pipelined poll --------
        const u64 ad = (u64)(h32 + buf * 512) + (u64)tid * 8ull;
        const unsigned want = (unsigned)(t + 1) & 0xffffu;
        u64 va[4], vb[4], vr[4];
        ISSUE4(va, ad);
        ISSUE4(vb, ad);
        for (;;) {
          // batch A retired (B still in flight)
          asm volatile("s_waitcnt vmcnt(4)" ::: "memory");
          __builtin_amdgcn_sched_barrier(0);
          {
            bool ok = true;
#pragma unroll
            for (int j = 0; j < 4; ++j) {
              ok &= (((unsigned)(va[j] >> 16) & 0xffffu) == want);
              ok &= ((unsigned)(va[j] >> 48) == want);
            }
            if (__all(ok)) {
#pragma unroll
              for (int j = 0; j < 4; ++j) vr[j] = va[j];
              break;
            }
          }
          ISSUE4(va, ad);
          // batch B retired (new A in flight)
          asm volatile("s_waitcnt vmcnt(4)" ::: "memory");
          __builtin_amdgcn_sched_barrier(0);
          {
            bool ok = true;
#pragma unroll
            for (int j = 0; j < 4; ++j) {
              ok &= (((unsigned)(vb[j] >> 16) & 0xffffu) == want);
              ok &= ((unsigned)(vb[j] >> 48) == want);
            }
            if (__all(ok)) {
#pragma unroll
              for (int j = 0; j < 4; ++j) vr[j] = vb[j];
              break;
            }
          }
          ISSUE4(vb, ad);
        }
        asm volatile("s_waitcnt vmcnt(0)" ::: "memory");  // drain stray batch
        __builtin_amdgcn_sched_barrier(0);
        // LDS broadcast (f32)
#pragma unroll
        for (int j = 0; j < 4; ++j) {
          const int k = (j * 64 + tid) * 2;
          union { unsigned u; float f; } f0, f1;
          f0.u = ((unsigned)vr[j]) << 16;
          f1.u = ((unsigned)(vr[j] >> 32)) << 16;
          hbuf[buf][haddr(k)]     = f0.f;
          hbuf[buf][haddr(k + 1)] = f1.f;
        }
      }
    }
    __syncthreads();  // S2 — h_{t+1} staged in LDS

    if (t + 1 < S_LEN) {
      const int base = s * 17;
#pragma unroll
      for (int i = 0; i < 16; ++i)
        h_reg[i] = hbuf[buf][base + i];
    }

    g_cur = g_nxt; g_nxt = g_new;
  }

  // stop burners: wg0 fans out private flags
  if (w == 0 && tid < NLAUNCH - NWG)
    __hip_atomic_store(done + tid * 8, 1u,
                       __ATOMIC_RELAXED, __HIP_MEMORY_SCOPE_AGENT);

  // ---------------- Phase 3: head (wg 0) ----------------
  if (w == 0) {
    __shared__ float hl[512];
    __shared__ float zl[128];
    {
      // final h_S: tag S_LEN in buf 0 (S even)
      unsigned v;
      do {
        v = __hip_atomic_load(&h32[tid], __ATOMIC_RELAXED, __HIP_MEMORY_SCOPE_AGENT);
      } while ((v >> 16) != (unsigned)(S_LEN & 0xffff) &&
               (v >> 16) != (unsigned)S_LEN);
      union { unsigned u; float f; } hu; hu.u = v << 16;
      hl[tid] = hu.f;
    }
    __syncthreads();
    const int j = tid >> 2, q = tid & 3;
    float sum = 0.f;
    const float4* w1v = (const float4*)(W1 + (size_t)j * 512 + q * 128);
#pragma unroll 8
    for (int k4 = 0; k4 < 32; ++k4) {
      const float4 v = w1v[k4];
      const int kb = q * 128 + k4 * 4;
      sum = __builtin_fmaf(v.x, hl[kb + 0], sum);
      sum = __builtin_fmaf(v.y, hl[kb + 1], sum);
      sum = __builtin_fmaf(v.z, hl[kb + 2], sum);
      sum = __builtin_fmaf(v.w, hl[kb + 3], sum);
    }
    sum += __shfl_xor(sum, 1);
    sum += __shfl_xor(sum, 2);
    if (q == 0) zl[j] = fsig(sum + b1[j]);
    __syncthreads();
    if (tid < 9) {
      float o = b2[tid];
      const float* w2r = W2 + tid * 128;
#pragma unroll 16
      for (int k = 0; k < 128; ++k) o = __builtin_fmaf(w2r[k], zl[k], o);
      out[tid] = fsig(o);
    }
  }
}

extern "C" void kernel_launch(void* const* d_in, const int* in_sizes, int n_in,
                              void* d_out, int out_size, void* d_ws, size_t ws_size,
                              hipStream_t stream) {
  const int*   x     = (const int*)d_in[0];
  const float* emb   = (const float*)d_in[1];
  const float* W_ih  = (const float*)d_in[2];
  const float* W_hh  = (const float*)d_in[3];
  const float* b_ih  = (const float*)d_in[4];
  const float* b_hh  = (const float*)d_in[5];
  const float* W1    = (const float*)d_in[6];
  const float* b1    = (const float*)d_in[7];
  const float* W2    = (const float*)d_in[8];
  const float* b2    = (const float*)d_in[9];
  float* out = (float*)d_out;

  const size_t gx_bytes = (size_t)S_LEN * 2048 * sizeof(unsigned short); // 64 MB
  const size_t h_off    = gx_bytes;                 // h32: 4 KB
  const size_t dn_off   = h_off + 4096;             // done flags: 48*32B
  if (ws_size < h_off + 16384) return;  // fail visibly

  unsigned short* gxp  = (unsigned short*)d_ws;
  unsigned int*   h32  = (unsigned int*)((char*)d_ws + h_off);
  unsigned int*   done = (unsigned int*)((char*)d_ws + dn_off);

  // reset tags + done every launch (graph replays don't re-poison ws)
  (void)hipMemsetAsync((char*)d_ws + h_off, 0, 16384, stream);

  dim3 g1(S_LEN / 64, 2048 / 64);
  gx_gemm<<<g1, 256, 0, stream>>>(x, emb, W_ih, b_ih, b_hh, gxp);
  lstm_rec<<<NLAUNCH, NTHR, 0, stream>>>(W_hh, gxp, W1, b1, W2, b2, out,
                                         h32, done);
}

// Round 17
// 43624.118 us; speedup vs baseline: 1.0620x; 1.0195x over previous
//
#include <hip/hip_runtime.h>
#include <hip/hip_bf16.h>

// LSTM: V=50000, E=512, H=512, S=16384, batch=1.
// Phase 1: gx[t][unit][gate] = emb[x[t]].W_ih + (b_ih+b_hh), bf16.
// Phase 2: 64 wgs: wg 0..15 = persistent recurrence; wg 16..63 = burners.
//          h exchange: 4B words (tag16<<16 | bf16 h); LDS stage -> ONE 128B-line
//          store per wg; poller wave: 2-deep pipelined polling with DEFERRED
//          stray-batch drain (drain overlaps next compute phase); LDS bcast.
// Phase 3: head MLP on wg 0.

#define S_LEN 16384
#define NWG   16
#define NLAUNCH 64
#define NTHR  512

typedef unsigned long long u64;
typedef float float4v __attribute__((ext_vector_type(4)));

static __device__ __forceinline__ float bf2f(unsigned int u16) {
  union { unsigned int i; float f; } v; v.i = u16 << 16; return v.f;
}
static __device__ __forceinline__ unsigned short f2bf(float f) {
  union { float f; unsigned int i; } v; v.f = f;
  unsigned int r = v.i + 0x7fffu + ((v.i >> 16) & 1u);
  return (unsigned short)(r >> 16);
}
static __device__ __forceinline__ float fsig(float x) { return 1.f / (1.f + __expf(-x)); }
static __device__ __forceinline__ float ftanh(float x) { return 2.f / (1.f + __expf(-2.f * x)) - 1.f; }

// LDS hbuf: h[k] at k + (k>>4)  (stride-17 rows: conflict-free)
static __device__ __forceinline__ int haddr(int k) { return k + (k >> 4); }

// issue 4 agent-scope loads (L1+L2 bypass), NO wait — caller manages vmcnt
#define ISSUE4(dst, ad)                                                     \
  asm volatile(                                                             \
      "global_load_dwordx2 %[v0], %[a], off sc0 sc1\n\t"                    \
      "global_load_dwordx2 %[v1], %[a], off offset:512 sc0 sc1\n\t"         \
      "global_load_dwordx2 %[v2], %[a], off offset:1024 sc0 sc1\n\t"        \
      "global_load_dwordx2 %[v3], %[a], off offset:1536 sc0 sc1"            \
      : [v0] "=&v"(dst[0]), [v1] "=&v"(dst[1]),                             \
        [v2] "=&v"(dst[2]), [v3] "=&v"(dst[3])                              \
      : [a] "v"(ad) : "memory")

// ---------------- Phase 1: gx GEMM ----------------
__global__ __launch_bounds__(256, 2) void gx_gemm(
    const int* __restrict__ x, const float* __restrict__ emb,
    const float* __restrict__ W_ih, const float* __restrict__ b_ih,
    const float* __restrict__ b_hh, unsigned short* __restrict__ gx)
{
  __shared__ float As[64][40];
  __shared__ float Bs[64][40];
  __shared__ int   xs[64];

  const int tid = threadIdx.x;
  const int bm = blockIdx.x;
  const int bn = blockIdx.y;

  if (tid < 64) xs[tid] = x[bm * 64 + tid];
  __syncthreads();

  float acc[4][4] = {};
  const int r0 = (tid >> 4) * 4;
  const int c0 = tid & 15;

  for (int kc = 0; kc < 512; kc += 32) {
#pragma unroll
    for (int h = 0; h < 2; ++h) {
      const int v = tid + h * 256;
      const int row = v >> 3, k4 = v & 7;
      const float4 av = *(const float4*)(emb + (size_t)xs[row] * 512 + kc + k4 * 4);
      As[row][k4 * 4 + 0] = av.x; As[row][k4 * 4 + 1] = av.y;
      As[row][k4 * 4 + 2] = av.z; As[row][k4 * 4 + 3] = av.w;
      const float4 bv = *(const float4*)(W_ih + (size_t)(bn * 64 + row) * 512 + kc + k4 * 4);
      Bs[row][k4 * 4 + 0] = bv.x; Bs[row][k4 * 4 + 1] = bv.y;
      Bs[row][k4 * 4 + 2] = bv.z; Bs[row][k4 * 4 + 3] = bv.w;
    }
    __syncthreads();
#pragma unroll
    for (int k4 = 0; k4 < 8; ++k4) {
      float4 a[4], b[4];
#pragma unroll
      for (int i = 0; i < 4; ++i) a[i] = *(const float4*)&As[r0 + i][k4 * 4];
#pragma unroll
      for (int j = 0; j < 4; ++j) b[j] = *(const float4*)&Bs[c0 + j * 16][k4 * 4];
#pragma unroll
      for (int i = 0; i < 4; ++i)
#pragma unroll
        for (int j = 0; j < 4; ++j) {
          acc[i][j] = __builtin_fmaf(a[i].x, b[j].x, acc[i][j]);
          acc[i][j] = __builtin_fmaf(a[i].y, b[j].y, acc[i][j]);
          acc[i][j] = __builtin_fmaf(a[i].z, b[j].z, acc[i][j]);
          acc[i][j] = __builtin_fmaf(a[i].w, b[j].w, acc[i][j]);
        }
    }
    __syncthreads();
  }

  // layout [t][unit][gate]: dst = t*2048 + (c&511)*4 + (c>>9)
#pragma unroll
  for (int j = 0; j < 4; ++j) {
    const int c = bn * 64 + c0 + j * 16;
    const float bias = b_ih[c] + b_hh[c];
    const size_t dstc = (size_t)(c & 511) * 4 + (size_t)(c >> 9);
#pragma unroll
    for (int i = 0; i < 4; ++i) {
      const size_t t = (size_t)bm * 64 + r0 + i;
      gx[t * 2048 + dstc] = f2bf(acc[i][j] + bias);
    }
  }
}

// ---------------- Phase 2: recurrence + light burners ----------------
// h32: [2 buf][512] u32 = (tag16<<16) | bf16(h).  One 128B line per wg.
__global__ __launch_bounds__(NTHR, 1) void lstm_rec(
    const float* __restrict__ W_hh, const unsigned short* __restrict__ gx,
    const float* __restrict__ W1, const float* __restrict__ b1,
    const float* __restrict__ W2, const float* __restrict__ b2,
    float* __restrict__ out,
    unsigned int* __restrict__ h32,
    unsigned int* __restrict__ done)
{
  const int tid = threadIdx.x;
  const int w   = blockIdx.x;

  // ---- burners: keep clocks awake; private flag, long burn interval ----
  if (w >= NWG) {
    unsigned int* myflag = done + (w - NWG) * 8;
    float a0 = (float)tid, a1 = a0 + 1.f, a2 = a0 + 2.f, a3 = a0 + 3.f;
    for (;;) {
      if (__hip_atomic_load(myflag, __ATOMIC_RELAXED, __HIP_MEMORY_SCOPE_AGENT))
        break;
#pragma unroll 32
      for (int i = 0; i < 2048; ++i) {
        a0 = __builtin_fmaf(a0, 1.0000001f, 1e-9f);
        a1 = __builtin_fmaf(a1, 0.9999999f, 1e-9f);
        a2 = __builtin_fmaf(a2, 1.0000002f, 1e-9f);
        a3 = __builtin_fmaf(a3, 0.9999998f, 1e-9f);
      }
    }
    asm volatile("" :: "v"(a0), "v"(a1), "v"(a2), "v"(a3));  // keep live
    return;
  }

  const int s    = tid & 31;          // K-slice: k in [s*16, s*16+16)
  const int half = (tid >> 5) & 1;
  const int wvi  = tid >> 6;          // wave 0..7
  const int ubase  = w * 32 + wvi * 4 + half * 2;
  const int ulocal = wvi * 4 + half * 2;

  // ---- weights pinned in regs via asm loads (non-rematerializable) ----
  float4v wvv[32];
#pragma unroll
  for (int q = 0; q < 8; ++q) {
    const int row = (q & 3) * 512 + ubase + (q >> 2);
    const float* src = W_hh + (size_t)row * 512 + s * 16;
#pragma unroll
    for (int i4 = 0; i4 < 4; ++i4) {
      asm volatile("global_load_dwordx4 %0, %1, off\n\ts_waitcnt vmcnt(0)"
                   : "=v"(wvv[q * 4 + i4]) : "v"((u64)(src + i4 * 4)) : "memory");
    }
  }

  __shared__ float hbuf[2][544];
  __shared__ unsigned int stage[32];

  float c0 = 0.f, c1 = 0.f;
  float h_reg[16];
#pragma unroll
  for (int i = 0; i < 16; ++i) h_reg[i] = 0.f;

  uint4 g_cur = {0,0,0,0}, g_nxt = {0,0,0,0};
  if (s == 0) {
    g_cur = *(const uint4*)(gx + (size_t)0 * 2048 + ubase * 4);
    g_nxt = *(const uint4*)(gx + (size_t)1 * 2048 + ubase * 4);
  }

  for (int t = 0; t < S_LEN; ++t) {
    uint4 g_new = {0,0,0,0};
    if (s == 0 && t + 2 < S_LEN)
      g_new = *(const uint4*)(gx + (size_t)(t + 2) * 2048 + ubase * 4);

    float acc[8];
#pragma unroll
    for (int q = 0; q < 8; ++q) {
      float a = 0.f;
#pragma unroll
      for (int i4 = 0; i4 < 4; ++i4) {
        const float4v vv = wvv[q * 4 + i4];
        a = __builtin_fmaf(vv.x, h_reg[i4 * 4 + 0], a);
        a = __builtin_fmaf(vv.y, h_reg[i4 * 4 + 1], a);
        a = __builtin_fmaf(vv.z, h_reg[i4 * 4 + 2], a);
        a = __builtin_fmaf(vv.w, h_reg[i4 * 4 + 3], a);
      }
      acc[q] = a;
    }
#pragma unroll
    for (int q = 0; q < 8; ++q) {
      float a = acc[q];
      a += __shfl_xor(a, 1);
      a += __shfl_xor(a, 2);
      a += __shfl_xor(a, 4);
      a += __shfl_xor(a, 8);
      a += __shfl_xor(a, 16);
      acc[q] = a;
    }

    const int buf = (t + 1) & 1;
    if (s == 0) {
      const float pi0 = acc[0] + bf2f(g_cur.x & 0xffffu);
      const float pf0 = acc[1] + bf2f(g_cur.x >> 16);
      const float pg0 = acc[2] + bf2f(g_cur.y & 0xffffu);
      const float po0 = acc[3] + bf2f(g_cur.y >> 16);
      const float pi1 = acc[4] + bf2f(g_cur.z & 0xffffu);
      const float pf1 = acc[5] + bf2f(g_cur.z >> 16);
      const float pg1 = acc[6] + bf2f(g_cur.w & 0xffffu);
      const float po1 = acc[7] + bf2f(g_cur.w >> 16);
      c0 = fsig(pf0) * c0 + fsig(pi0) * ftanh(pg0);
      c1 = fsig(pf1) * c1 + fsig(pi1) * ftanh(pg1);
      const float h0 = fsig(po0) * ftanh(c0);
      const float h1 = fsig(po1) * ftanh(c1);
      const unsigned tg16 = (unsigned)(t + 1) << 16;
      const u64 pk = ((u64)(tg16 | (unsigned)f2bf(h1)) << 32)
                   |  (u64)(tg16 | (unsigned)f2bf(h0));
      *(u64*)&stage[ulocal] = pk;     // 8B aligned (ulocal even)
    }
    __syncthreads();  // S1 — stage complete

    if (tid < 64) {
      // condensed publish: ONE instruction, 16 lanes x 8B = the wg's 128B line
      if (tid < 16) {
        const u64 sv = *(const u64*)&stage[tid * 2];
        __hip_atomic_store((u64*)&h32[buf * 512 + w * 32] + tid, sv,
                           __ATOMIC_RELAXED, __HIP_MEMORY_SCOPE_AGENT);
      }
      if (t + 1 < S_LEN) {
        // -------- 2-deep pipelined poll, deferred stray drain --------
        const u64 ad = (u64)(h32 + buf * 512) + (u64)tid * 8ull;
        const unsigned want = (unsigned)(t + 1) & 0xffffu;
        u64 va[4], vb[4], vr[4];
        // retire last step's stray batch (aged a full compute phase: ~free);
        // the 2 fresh publish stores stay in flight.
        asm volatile("s_waitcnt vmcnt(2)" ::: "memory");
        __builtin_amdgcn_sched_barrier(0);
        ISSUE4(va, ad);
        ISSUE4(vb, ad);
        for (;;) {
          // retires {stores + batch A} first pass, then alternates batches
          asm volatile("s_waitcnt vmcnt(4)" ::: "memory");
          __builtin_amdgcn_sched_barrier(0);
          {
            bool ok = true;
#pragma unroll
            for (int j = 0; j < 4; ++j) {
              ok &= (((unsigned)(va[j] >> 16) & 0xffffu) == want);
              ok &= ((unsigned)(va[j] >> 48) == want);
            }
            if (__all(ok)) {
#pragma unroll
              for (int j = 0; j < 4; ++j) vr[j] = va[j];
              break;
            }
          }
          ISSUE4(va, ad);
          asm volatile("s_waitcnt vmcnt(4)" ::: "memory");
          __builtin_amdgcn_sched_barrier(0);
          {
            bool ok = true;
#pragma unroll
            for (int j = 0; j < 4; ++j) {
              ok &= (((unsigned)(vb[j] >> 16) & 0xffffu) == want);
              ok &= ((unsigned)(vb[j] >> 48) == want);
            }
            if (__all(ok)) {
#pragma unroll
              for (int j = 0; j < 4; ++j) vr[j] = vb[j];
              break;
            }
          }
          ISSUE4(vb, ad);
        }
        // NO drain here — stray batch retires during next compute phase.
        // LDS broadcast (f32)
#pragma unroll
        for (int j = 0; j < 4; ++j) {
          const int k = (j * 64 + tid) * 2;
          union { unsigned u; float f; } f0, f1;
          f0.u = ((unsigned)vr[j]) << 16;
          f1.u = ((unsigned)(vr[j] >> 32)) << 16;
          hbuf[buf][haddr(k)]     = f0.f;
          hbuf[buf][haddr(k + 1)] = f1.f;
        }
      }
    }
    __syncthreads();  // S2 — h_{t+1} staged in LDS

    if (t + 1 < S_LEN) {
      const int base = s * 17;
#pragma unroll
      for (int i = 0; i < 16; ++i)
        h_reg[i] = hbuf[buf][base + i];
    }

    g_cur = g_nxt; g_nxt = g_new;
  }

  // safety drain: stray poll batch must land before its registers are reused
  if (tid < 64)
    asm volatile("s_waitcnt vmcnt(0)" ::: "memory");

  // stop burners: wg0 fans out private flags
  if (w == 0 && tid < NLAUNCH - NWG)
    __hip_atomic_store(done + tid * 8, 1u,
                       __ATOMIC_RELAXED, __HIP_MEMORY_SCOPE_AGENT);

  // ---------------- Phase 3: head (wg 0) ----------------
  if (w == 0) {
    __shared__ float hl[512];
    __shared__ float zl[128];
    {
      // final h_S: tag S_LEN in buf 0 (S even)
      unsigned v;
      do {
        v = __hip_atomic_load(&h32[tid], __ATOMIC_RELAXED, __HIP_MEMORY_SCOPE_AGENT);
      } while ((v >> 16) != (unsigned)S_LEN);
      union { unsigned u; float f; } hu; hu.u = v << 16;
      hl[tid] = hu.f;
    }
    __syncthreads();
    const int j = tid >> 2, q = tid & 3;
    float sum = 0.f;
    const float4* w1v = (const float4*)(W1 + (size_t)j * 512 + q * 128);
#pragma unroll 8
    for (int k4 = 0; k4 < 32; ++k4) {
      const float4 v = w1v[k4];
      const int kb = q * 128 + k4 * 4;
      sum = __builtin_fmaf(v.x, hl[kb + 0], sum);
      sum = __builtin_fmaf(v.y, hl[kb + 1], sum);
      sum = __builtin_fmaf(v.z, hl[kb + 2], sum);
      sum = __builtin_fmaf(v.w, hl[kb + 3], sum);
    }
    sum += __shfl_xor(sum, 1);
    sum += __shfl_xor(sum, 2);
    if (q == 0) zl[j] = fsig(sum + b1[j]);
    __syncthreads();
    if (tid < 9) {
      float o = b2[tid];
      const float* w2r = W2 + tid * 128;
#pragma unroll 16
      for (int k = 0; k < 128; ++k) o = __builtin_fmaf(w2r[k], zl[k], o);
      out[tid] = fsig(o);
    }
  }
}

extern "C" void kernel_launch(void* const* d_in, const int* in_sizes, int n_in,
                              void* d_out, int out_size, void* d_ws, size_t ws_size,
                              hipStream_t stream) {
  const int*   x     = (const int*)d_in[0];
  const float* emb   = (const float*)d_in[1];
  const float* W_ih  = (const float*)d_in[2];
  const float* W_hh  = (const float*)d_in[3];
  const float* b_ih  = (const float*)d_in[4];
  const float* b_hh  = (const float*)d_in[5];
  const float* W1    = (const float*)d_in[6];
  const float* b1    = (const float*)d_in[7];
  const float* W2    = (const float*)d_in[8];
  const float* b2    = (const float*)d_in[9];
  float* out = (float*)d_out;

  const size_t gx_bytes = (size_t)S_LEN * 2048 * sizeof(unsigned short); // 64 MB
  const size_t h_off    = gx_bytes;                 // h32: 4 KB
  const size_t dn_off   = h_off + 4096;             // done flags: 48*32B
  if (ws_size < h_off + 16384) return;  // fail visibly

  unsigned short* gxp  = (unsigned short*)d_ws;
  unsigned int*   h32  = (unsigned int*)((char*)d_ws + h_off);
  unsigned int*   done = (unsigned int*)((char*)d_ws + dn_off);

  // reset tags + done every launch (graph replays don't re-poison ws)
  (void)hipMemsetAsync((char*)d_ws + h_off, 0, 16384, stream);

  dim3 g1(S_LEN / 64, 2048 / 64);
  gx_gemm<<<g1, 256, 0, stream>>>(x, emb, W_ih, b_ih, b_hh, gxp);
  lstm_rec<<<NLAUNCH, NTHR, 0, stream>>>(W_hh, gxp, W1, b1, W2, b2, out,
                                         h32, done);
}